// Round 3
// baseline (120.210 us; speedup 1.0000x reference)
//
#include <hip/hip_runtime.h>
#include <cfloat>

#define GPB 4   // graphs per block in kernel B

// ---------------------------------------------------------------------------
// Kernel A: streaming boundary detection over the SORTED edge_batch.
// seg[g] = first index i with eb[i] >= g (= count of elements < g); seg[G]=E.
// For each adjacent pair (eb[i], eb[i+1]]: seg[g'] = i+1. Pure 8 MB stream,
// ~1.3 us, vs ~5-6 us for the 21-deep dependent binary-search chain.
// ---------------------------------------------------------------------------
__global__ __launch_bounds__(256) void seg_bounds_stream(
    const int* __restrict__ eb, int E, int G, int* __restrict__ seg)
{
    int i = blockIdx.x * blockDim.x + threadIdx.x;
    if (i >= E) return;
    int b0 = eb[i];
    int b1 = (i + 1 < E) ? eb[i + 1] : G;
    if (i == 0)
        for (int g = 0; g <= b0; ++g) seg[g] = 0;   // prefix (empty leading graphs)
    for (int g = b0; g < b1; ++g) seg[g + 1] = i + 1;
}

// ---------------------------------------------------------------------------
// Wave-level butterfly reductions across the 4 row-slots held by one wave.
// Lane l of a wave holds slot (l>>4), feature-col (l&15). After xor-16 and
// xor-32 every lane holds the reduction over all 4 slots at its f-column.
// ---------------------------------------------------------------------------
__device__ __forceinline__ float4 wred_add(float4 v) {
    v.x += __shfl_xor(v.x, 16); v.y += __shfl_xor(v.y, 16);
    v.z += __shfl_xor(v.z, 16); v.w += __shfl_xor(v.w, 16);
    v.x += __shfl_xor(v.x, 32); v.y += __shfl_xor(v.y, 32);
    v.z += __shfl_xor(v.z, 32); v.w += __shfl_xor(v.w, 32);
    return v;
}
__device__ __forceinline__ float4 wred_max(float4 v) {
    v.x = fmaxf(v.x, __shfl_xor(v.x, 16)); v.y = fmaxf(v.y, __shfl_xor(v.y, 16));
    v.z = fmaxf(v.z, __shfl_xor(v.z, 16)); v.w = fmaxf(v.w, __shfl_xor(v.w, 16));
    v.x = fmaxf(v.x, __shfl_xor(v.x, 32)); v.y = fmaxf(v.y, __shfl_xor(v.y, 32));
    v.z = fmaxf(v.z, __shfl_xor(v.z, 32)); v.w = fmaxf(v.w, __shfl_xor(v.w, 32));
    return v;
}
__device__ __forceinline__ float4 wred_min(float4 v) {
    v.x = fminf(v.x, __shfl_xor(v.x, 16)); v.y = fminf(v.y, __shfl_xor(v.y, 16));
    v.z = fminf(v.z, __shfl_xor(v.z, 16)); v.w = fminf(v.w, __shfl_xor(v.w, 16));
    v.x = fminf(v.x, __shfl_xor(v.x, 32)); v.y = fminf(v.y, __shfl_xor(v.y, 32));
    v.z = fminf(v.z, __shfl_xor(v.z, 32)); v.w = fminf(v.w, __shfl_xor(v.w, 32));
    return v;
}

#define ACC(v)                                                            \
    do {                                                                  \
        sum.x += (v).x; sum.y += (v).y; sum.z += (v).z; sum.w += (v).w;   \
        sq.x += (v).x * (v).x; sq.y += (v).y * (v).y;                     \
        sq.z += (v).z * (v).z; sq.w += (v).w * (v).w;                     \
        mx.x = fmaxf(mx.x, (v).x); mx.y = fmaxf(mx.y, (v).y);             \
        mx.z = fmaxf(mx.z, (v).z); mx.w = fmaxf(mx.w, (v).w);             \
        mn.x = fminf(mn.x, (v).x); mn.y = fminf(mn.y, (v).y);             \
        mn.z = fminf(mn.z, (v).z); mn.w = fminf(mn.w, (v).w);             \
    } while (0)

// ---------------------------------------------------------------------------
// Kernel B: one block = GPB consecutive graphs (contiguous edge range).
// 256 threads = 16 row-slots x 16 float4 cols per graph. Per graph:
// stream rows (unroll-4), shfl-butterfly within wave, 4 KB double-buffered
// LDS combine with ONE barrier, finalize as a single full-wave 1 KB store
// (out float4 [32,96) = mean|var|max|min is contiguous).
// Output row layout (float4 units, 160/row):
//   [0:32)=metadata [32:48)=mean [48:64)=var [64:80)=max [80:96)=min
//   [96:128)=attended [128:160)=current
// ---------------------------------------------------------------------------
__global__ __launch_bounds__(256) void graph_embed_kernel(
    const float4* __restrict__ edges,  // E x 16 float4
    const float4* __restrict__ meta,   // G x 32 float4
    const float4* __restrict__ att,    // G x 32 float4
    const float4* __restrict__ cur,    // G x 32 float4
    const int*    __restrict__ seg,    // G+1
    float4*       __restrict__ out,    // G x 160 float4
    int G)
{
    const int tid  = threadIdx.x;
    const int g4   = blockIdx.x * GPB;
    const int f    = tid & 15;   // float4 column (also: fi in finalize)
    const int r    = tid >> 4;   // row slot 0..15 (also: stat in finalize)
    const int lane = tid & 63;
    const int w    = tid >> 6;

    // Passthrough copies for all GPB graphs, issued first (overlaps the scan).
    for (int t = tid; t < 96 * GPB; t += 256) {
        const int j = t / 96, k = t % 96;
        const size_t ob = (size_t)(g4 + j) * 160;
        const size_t ib = (size_t)(g4 + j) * 32;
        const int sel = k >> 5, kk = k & 31;
        if (sel == 0)      out[ob +       kk] = meta[ib + kk];
        else if (sel == 1) out[ob +  96 + kk] = att [ib + kk];
        else               out[ob + 128 + kk] = cur [ib + kk];
    }

    int starts[GPB + 1];
    #pragma unroll
    for (int k = 0; k <= GPB; ++k)
        starts[k] = seg[min(g4 + k, G)];

    __shared__ float4 sred[2][4][4][16];  // [buf][stat][wave][f] = 8 KB

    #pragma unroll
    for (int j = 0; j < GPB; ++j) {
        if (g4 + j >= G) break;
        const int start = starts[j];
        const int end   = starts[j + 1];
        const int count = end - start;

        float4 sum = make_float4(0.f, 0.f, 0.f, 0.f);
        float4 sq  = make_float4(0.f, 0.f, 0.f, 0.f);
        float4 mx  = make_float4(-FLT_MAX, -FLT_MAX, -FLT_MAX, -FLT_MAX);
        float4 mn  = make_float4( FLT_MAX,  FLT_MAX,  FLT_MAX,  FLT_MAX);

        int row = start + r;
        for (; row + 48 < end; row += 64) {       // 4 loads in flight
            float4 v0 = edges[(size_t)(row     ) * 16 + f];
            float4 v1 = edges[(size_t)(row + 16) * 16 + f];
            float4 v2 = edges[(size_t)(row + 32) * 16 + f];
            float4 v3 = edges[(size_t)(row + 48) * 16 + f];
            ACC(v0); ACC(v1); ACC(v2); ACC(v3);
        }
        for (; row < end; row += 16) {
            float4 v = edges[(size_t)row * 16 + f];
            ACC(v);
        }

        sum = wred_add(sum);
        sq  = wred_add(sq);
        mx  = wred_max(mx);
        mn  = wred_min(mn);

        const int buf = j & 1;
        if (lane < 16) {
            sred[buf][0][w][lane] = sum;
            sred[buf][1][w][lane] = sq;
            sred[buf][2][w][lane] = mx;
            sred[buf][3][w][lane] = mn;
        }
        __syncthreads();   // one barrier per graph (double-buffered LDS)

        if (tid < 64) {
            float4 res;
            if (count == 0) {
                res = make_float4(0.f, 0.f, 0.f, 0.f);
            } else if (r < 2) {          // mean (r==0) or var (r==1)
                float4 S = sred[buf][0][0][f];
                float4 b1 = sred[buf][0][1][f], b2 = sred[buf][0][2][f], b3 = sred[buf][0][3][f];
                S.x += b1.x + b2.x + b3.x; S.y += b1.y + b2.y + b3.y;
                S.z += b1.z + b2.z + b3.z; S.w += b1.w + b2.w + b3.w;
                const float inv = 1.0f / (float)count;
                float4 mean = make_float4(S.x * inv, S.y * inv, S.z * inv, S.w * inv);
                if (r == 0) {
                    res = mean;
                } else {
                    float4 Q = sred[buf][1][0][f];
                    float4 c1 = sred[buf][1][1][f], c2 = sred[buf][1][2][f], c3 = sred[buf][1][3][f];
                    Q.x += c1.x + c2.x + c3.x; Q.y += c1.y + c2.y + c3.y;
                    Q.z += c1.z + c2.z + c3.z; Q.w += c1.w + c2.w + c3.w;
                    res.x = fmaxf(Q.x * inv - mean.x * mean.x, 0.f);
                    res.y = fmaxf(Q.y * inv - mean.y * mean.y, 0.f);
                    res.z = fmaxf(Q.z * inv - mean.z * mean.z, 0.f);
                    res.w = fmaxf(Q.w * inv - mean.w * mean.w, 0.f);
                }
            } else if (r == 2) {         // max
                float4 X = sred[buf][2][0][f];
                float4 d1 = sred[buf][2][1][f], d2 = sred[buf][2][2][f], d3 = sred[buf][2][3][f];
                X.x = fmaxf(fmaxf(X.x, d1.x), fmaxf(d2.x, d3.x));
                X.y = fmaxf(fmaxf(X.y, d1.y), fmaxf(d2.y, d3.y));
                X.z = fmaxf(fmaxf(X.z, d1.z), fmaxf(d2.z, d3.z));
                X.w = fmaxf(fmaxf(X.w, d1.w), fmaxf(d2.w, d3.w));
                res = X;
            } else {                     // min
                float4 N = sred[buf][3][0][f];
                float4 e1 = sred[buf][3][1][f], e2 = sred[buf][3][2][f], e3 = sred[buf][3][3][f];
                N.x = fminf(fminf(N.x, e1.x), fminf(e2.x, e3.x));
                N.y = fminf(fminf(N.y, e1.y), fminf(e2.y, e3.y));
                N.z = fminf(fminf(N.z, e1.z), fminf(e2.z, e3.z));
                N.w = fminf(fminf(N.w, e1.w), fminf(e2.w, e3.w));
                res = N;
            }
            // [32,96) float4 = mean|var|max|min contiguous -> one 1 KB wave store
            out[(size_t)(g4 + j) * 160 + 32 + tid] = res;
        }
        // No trailing barrier: next graph writes sred[buf^1]; wave 0 can't be
        // lapped because every wave must pass the NEXT graph's barrier (which
        // follows wave 0's reads in its own program order) before writing buf.
    }
}

extern "C" void kernel_launch(void* const* d_in, const int* in_sizes, int n_in,
                              void* d_out, int out_size, void* d_ws, size_t ws_size,
                              hipStream_t stream)
{
    const float* h_edges = (const float*)d_in[0];
    const float* h_meta  = (const float*)d_in[1];
    const float* h_att   = (const float*)d_in[2];
    const float* h_cur   = (const float*)d_in[3];
    const int*   e_batch = (const int*)d_in[4];

    const int E = in_sizes[4];          // 2,000,000
    const int G = in_sizes[1] / 128;    // 8192

    int* seg = (int*)d_ws;              // (G+1) ints of scratch

    seg_bounds_stream<<<(E + 255) / 256, 256, 0, stream>>>(e_batch, E, G, seg);

    const int nblk = (G + GPB - 1) / GPB;   // 2048 -> exactly 8 blocks/CU
    graph_embed_kernel<<<nblk, 256, 0, stream>>>(
        (const float4*)h_edges, (const float4*)h_meta, (const float4*)h_att,
        (const float4*)h_cur, seg, (float4*)d_out, G);
}

// Round 4
// 108.401 us; speedup vs baseline: 1.1089x; 1.1089x over previous
//
#include <hip/hip_runtime.h>
#include <cfloat>

#define GPB 4   // graphs per block in kernel B

typedef float f4 __attribute__((ext_vector_type(4)));

__device__ __forceinline__ f4 ntl(const f4* p) {
    return __builtin_nontemporal_load(p);
}
__device__ __forceinline__ void nts(f4* p, f4 v) {
    __builtin_nontemporal_store(v, p);
}

// ---------------------------------------------------------------------------
// Kernel A: streaming boundary detection over the SORTED edge_batch.
// seg[g] = first index i with eb[i] >= g; seg[G]=E. Plain (cached) loads so
// the eb[i+1] re-read hits L1. Proven off the critical path (R2->R3 neutral).
// ---------------------------------------------------------------------------
__global__ __launch_bounds__(256) void seg_bounds_stream(
    const int* __restrict__ eb, int E, int G, int* __restrict__ seg)
{
    int i = blockIdx.x * blockDim.x + threadIdx.x;
    if (i >= E) return;
    int b0 = eb[i];
    int b1 = (i + 1 < E) ? eb[i + 1] : G;
    if (i == 0)
        for (int g = 0; g <= b0; ++g) seg[g] = 0;
    for (int g = b0; g < b1; ++g) seg[g + 1] = i + 1;
}

// Wave-level butterfly across the 4 row-slots held by one wave.
__device__ __forceinline__ f4 wred_add(f4 v) {
    v[0] += __shfl_xor(v[0], 16); v[1] += __shfl_xor(v[1], 16);
    v[2] += __shfl_xor(v[2], 16); v[3] += __shfl_xor(v[3], 16);
    v[0] += __shfl_xor(v[0], 32); v[1] += __shfl_xor(v[1], 32);
    v[2] += __shfl_xor(v[2], 32); v[3] += __shfl_xor(v[3], 32);
    return v;
}
__device__ __forceinline__ f4 wred_max(f4 v) {
    v[0] = fmaxf(v[0], __shfl_xor(v[0], 16)); v[1] = fmaxf(v[1], __shfl_xor(v[1], 16));
    v[2] = fmaxf(v[2], __shfl_xor(v[2], 16)); v[3] = fmaxf(v[3], __shfl_xor(v[3], 16));
    v[0] = fmaxf(v[0], __shfl_xor(v[0], 32)); v[1] = fmaxf(v[1], __shfl_xor(v[1], 32));
    v[2] = fmaxf(v[2], __shfl_xor(v[2], 32)); v[3] = fmaxf(v[3], __shfl_xor(v[3], 32));
    return v;
}
__device__ __forceinline__ f4 wred_min(f4 v) {
    v[0] = fminf(v[0], __shfl_xor(v[0], 16)); v[1] = fminf(v[1], __shfl_xor(v[1], 16));
    v[2] = fminf(v[2], __shfl_xor(v[2], 16)); v[3] = fminf(v[3], __shfl_xor(v[3], 16));
    v[0] = fminf(v[0], __shfl_xor(v[0], 32)); v[1] = fminf(v[1], __shfl_xor(v[1], 32));
    v[2] = fminf(v[2], __shfl_xor(v[2], 32)); v[3] = fminf(v[3], __shfl_xor(v[3], 32));
    return v;
}

#define ACC(v)                                                            \
    do {                                                                  \
        sum += (v);                                                       \
        sq  += (v) * (v);                                                 \
        mx[0] = fmaxf(mx[0], (v)[0]); mx[1] = fmaxf(mx[1], (v)[1]);       \
        mx[2] = fmaxf(mx[2], (v)[2]); mx[3] = fmaxf(mx[3], (v)[3]);       \
        mn[0] = fminf(mn[0], (v)[0]); mn[1] = fminf(mn[1], (v)[1]);       \
        mn[2] = fminf(mn[2], (v)[2]); mn[3] = fminf(mn[3], (v)[3]);       \
    } while (0)

// ---------------------------------------------------------------------------
// Kernel B: one block = GPB consecutive graphs. 256 threads = 16 row-slots x
// 16 f4 cols. All streaming traffic (edges in, out writes, passthrough) uses
// the nontemporal (nt) cache policy: zero-reuse data bypasses L1/L2
// allocation instead of thrashing it. Structure identical to R3 (proven
// neutral) to isolate the NT effect.
// Output row layout (f4 units, 160/row):
//   [0:32)=metadata [32:48)=mean [48:64)=var [64:80)=max [80:96)=min
//   [96:128)=attended [128:160)=current
// ---------------------------------------------------------------------------
__global__ __launch_bounds__(256) void graph_embed_kernel(
    const f4* __restrict__ edges,  // E x 16 f4
    const f4* __restrict__ meta,   // G x 32 f4
    const f4* __restrict__ att,    // G x 32 f4
    const f4* __restrict__ cur,    // G x 32 f4
    const int* __restrict__ seg,   // G+1
    f4*       __restrict__ out,    // G x 160 f4
    int G)
{
    const int tid  = threadIdx.x;
    const int g4   = blockIdx.x * GPB;
    const int f    = tid & 15;   // f4 column
    const int r    = tid >> 4;   // row slot 0..15
    const int lane = tid & 63;
    const int w    = tid >> 6;

    // Passthrough copies (zero reuse -> NT both directions), issued first.
    for (int t = tid; t < 96 * GPB; t += 256) {
        const int j = t / 96, k = t % 96;
        const size_t ob = (size_t)(g4 + j) * 160;
        const size_t ib = (size_t)(g4 + j) * 32;
        const int sel = k >> 5, kk = k & 31;
        if (sel == 0)      nts(&out[ob +       kk], ntl(&meta[ib + kk]));
        else if (sel == 1) nts(&out[ob +  96 + kk], ntl(&att [ib + kk]));
        else               nts(&out[ob + 128 + kk], ntl(&cur [ib + kk]));
    }

    int starts[GPB + 1];
    #pragma unroll
    for (int k = 0; k <= GPB; ++k)
        starts[k] = seg[min(g4 + k, G)];

    __shared__ f4 sred[2][4][4][16];  // [buf][stat][wave][f] = 8 KB

    #pragma unroll
    for (int j = 0; j < GPB; ++j) {
        if (g4 + j >= G) break;
        const int start = starts[j];
        const int end   = starts[j + 1];
        const int count = end - start;

        f4 sum = (f4)(0.f);
        f4 sq  = (f4)(0.f);
        f4 mx  = (f4)(-FLT_MAX);
        f4 mn  = (f4)( FLT_MAX);

        int row = start + r;
        for (; row + 48 < end; row += 64) {       // 4 NT loads in flight
            f4 v0 = ntl(&edges[(size_t)(row     ) * 16 + f]);
            f4 v1 = ntl(&edges[(size_t)(row + 16) * 16 + f]);
            f4 v2 = ntl(&edges[(size_t)(row + 32) * 16 + f]);
            f4 v3 = ntl(&edges[(size_t)(row + 48) * 16 + f]);
            ACC(v0); ACC(v1); ACC(v2); ACC(v3);
        }
        for (; row < end; row += 16) {
            f4 v = ntl(&edges[(size_t)row * 16 + f]);
            ACC(v);
        }

        sum = wred_add(sum);
        sq  = wred_add(sq);
        mx  = wred_max(mx);
        mn  = wred_min(mn);

        const int buf = j & 1;
        if (lane < 16) {
            sred[buf][0][w][lane] = sum;
            sred[buf][1][w][lane] = sq;
            sred[buf][2][w][lane] = mx;
            sred[buf][3][w][lane] = mn;
        }
        __syncthreads();   // one barrier per graph (double-buffered LDS)

        if (tid < 64) {
            f4 res;
            if (count == 0) {
                res = (f4)(0.f);
            } else if (r < 2) {          // mean (r==0) or var (r==1)
                f4 S = sred[buf][0][0][f] + sred[buf][0][1][f]
                     + sred[buf][0][2][f] + sred[buf][0][3][f];
                const float inv = 1.0f / (float)count;
                f4 mean = S * inv;
                if (r == 0) {
                    res = mean;
                } else {
                    f4 Q = sred[buf][1][0][f] + sred[buf][1][1][f]
                         + sred[buf][1][2][f] + sred[buf][1][3][f];
                    f4 var = Q * inv - mean * mean;
                    res[0] = fmaxf(var[0], 0.f); res[1] = fmaxf(var[1], 0.f);
                    res[2] = fmaxf(var[2], 0.f); res[3] = fmaxf(var[3], 0.f);
                }
            } else if (r == 2) {         // max
                f4 a = sred[buf][2][0][f], b = sred[buf][2][1][f];
                f4 c = sred[buf][2][2][f], d = sred[buf][2][3][f];
                res[0] = fmaxf(fmaxf(a[0], b[0]), fmaxf(c[0], d[0]));
                res[1] = fmaxf(fmaxf(a[1], b[1]), fmaxf(c[1], d[1]));
                res[2] = fmaxf(fmaxf(a[2], b[2]), fmaxf(c[2], d[2]));
                res[3] = fmaxf(fmaxf(a[3], b[3]), fmaxf(c[3], d[3]));
            } else {                     // min
                f4 a = sred[buf][3][0][f], b = sred[buf][3][1][f];
                f4 c = sred[buf][3][2][f], d = sred[buf][3][3][f];
                res[0] = fminf(fminf(a[0], b[0]), fminf(c[0], d[0]));
                res[1] = fminf(fminf(a[1], b[1]), fminf(c[1], d[1]));
                res[2] = fminf(fminf(a[2], b[2]), fminf(c[2], d[2]));
                res[3] = fminf(fminf(a[3], b[3]), fminf(c[3], d[3]));
            }
            // [32,96) f4 = mean|var|max|min contiguous -> one 1 KB wave NT store
            nts(&out[(size_t)(g4 + j) * 160 + 32 + tid], res);
        }
        // No trailing barrier needed: next graph uses sred[buf^1].
    }
}

extern "C" void kernel_launch(void* const* d_in, const int* in_sizes, int n_in,
                              void* d_out, int out_size, void* d_ws, size_t ws_size,
                              hipStream_t stream)
{
    const float* h_edges = (const float*)d_in[0];
    const float* h_meta  = (const float*)d_in[1];
    const float* h_att   = (const float*)d_in[2];
    const float* h_cur   = (const float*)d_in[3];
    const int*   e_batch = (const int*)d_in[4];

    const int E = in_sizes[4];          // 2,000,000
    const int G = in_sizes[1] / 128;    // 8192

    int* seg = (int*)d_ws;              // (G+1) ints of scratch

    seg_bounds_stream<<<(E + 255) / 256, 256, 0, stream>>>(e_batch, E, G, seg);

    const int nblk = (G + GPB - 1) / GPB;   // 2048 -> exactly 8 blocks/CU
    graph_embed_kernel<<<nblk, 256, 0, stream>>>(
        (const f4*)h_edges, (const f4*)h_meta, (const f4*)h_att,
        (const f4*)h_cur, seg, (f4*)d_out, G);
}

// Round 5
// 107.841 us; speedup vs baseline: 1.1147x; 1.0052x over previous
//
#include <hip/hip_runtime.h>
#include <cfloat>

#define GPB 4   // graphs per block in kernel B

typedef float f4 __attribute__((ext_vector_type(4)));

__device__ __forceinline__ f4 ntl(const f4* p) {
    return __builtin_nontemporal_load(p);
}
__device__ __forceinline__ void nts(f4* p, f4 v) {
    __builtin_nontemporal_store(v, p);
}

// ---------------------------------------------------------------------------
// Kernel A: streaming boundary detection over the SORTED edge_batch.
// seg[g] = first index i with eb[i] >= g; seg[G]=E. Cached loads: eb[i+1]
// re-read hits L1. Proven off the critical path (R2->R3 neutral).
// ---------------------------------------------------------------------------
__global__ __launch_bounds__(256) void seg_bounds_stream(
    const int* __restrict__ eb, int E, int G, int* __restrict__ seg)
{
    int i = blockIdx.x * blockDim.x + threadIdx.x;
    if (i >= E) return;
    int b0 = eb[i];
    int b1 = (i + 1 < E) ? eb[i + 1] : G;
    if (i == 0)
        for (int g = 0; g <= b0; ++g) seg[g] = 0;
    for (int g = b0; g < b1; ++g) seg[g + 1] = i + 1;
}

// Wave-level butterfly across the 4 row-slots held by one wave.
__device__ __forceinline__ f4 wred_add(f4 v) {
    v[0] += __shfl_xor(v[0], 16); v[1] += __shfl_xor(v[1], 16);
    v[2] += __shfl_xor(v[2], 16); v[3] += __shfl_xor(v[3], 16);
    v[0] += __shfl_xor(v[0], 32); v[1] += __shfl_xor(v[1], 32);
    v[2] += __shfl_xor(v[2], 32); v[3] += __shfl_xor(v[3], 32);
    return v;
}
__device__ __forceinline__ f4 wred_max(f4 v) {
    v[0] = fmaxf(v[0], __shfl_xor(v[0], 16)); v[1] = fmaxf(v[1], __shfl_xor(v[1], 16));
    v[2] = fmaxf(v[2], __shfl_xor(v[2], 16)); v[3] = fmaxf(v[3], __shfl_xor(v[3], 16));
    v[0] = fmaxf(v[0], __shfl_xor(v[0], 32)); v[1] = fmaxf(v[1], __shfl_xor(v[1], 32));
    v[2] = fmaxf(v[2], __shfl_xor(v[2], 32)); v[3] = fmaxf(v[3], __shfl_xor(v[3], 32));
    return v;
}
__device__ __forceinline__ f4 wred_min(f4 v) {
    v[0] = fminf(v[0], __shfl_xor(v[0], 16)); v[1] = fminf(v[1], __shfl_xor(v[1], 16));
    v[2] = fminf(v[2], __shfl_xor(v[2], 16)); v[3] = fminf(v[3], __shfl_xor(v[3], 16));
    v[0] = fminf(v[0], __shfl_xor(v[0], 32)); v[1] = fminf(v[1], __shfl_xor(v[1], 32));
    v[2] = fminf(v[2], __shfl_xor(v[2], 32)); v[3] = fminf(v[3], __shfl_xor(v[3], 32));
    return v;
}

#define ACC(v)                                                            \
    do {                                                                  \
        sum += (v);                                                       \
        sq  += (v) * (v);                                                 \
        mx[0] = fmaxf(mx[0], (v)[0]); mx[1] = fmaxf(mx[1], (v)[1]);       \
        mx[2] = fmaxf(mx[2], (v)[2]); mx[3] = fmaxf(mx[3], (v)[3]);       \
        mn[0] = fminf(mn[0], (v)[0]); mn[1] = fminf(mn[1], (v)[1]);       \
        mn[2] = fminf(mn[2], (v)[2]); mn[3] = fminf(mn[3], (v)[3]);       \
    } while (0)

// ---------------------------------------------------------------------------
// Kernel B: one block = GPB consecutive graphs. 256 threads = 16 row-slots x
// 16 f4 cols. All zero-reuse traffic uses NT cache policy (R4: -10%).
// __launch_bounds__(256, 8): cap VGPRs at 64 so all 2048 blocks fit as one
// resident generation (8 blocks/CU = 32 waves/CU) — no low-occupancy tail.
// Live-set arithmetic: 16 accum + 16 in-flight + ~10 addr ≈ 42 VGPR, fits.
// Output row layout (f4 units, 160/row):
//   [0:32)=metadata [32:48)=mean [48:64)=var [64:80)=max [80:96)=min
//   [96:128)=attended [128:160)=current
// ---------------------------------------------------------------------------
__global__ __launch_bounds__(256, 8) void graph_embed_kernel(
    const f4* __restrict__ edges,  // E x 16 f4
    const f4* __restrict__ meta,   // G x 32 f4
    const f4* __restrict__ att,    // G x 32 f4
    const f4* __restrict__ cur,    // G x 32 f4
    const int* __restrict__ seg,   // G+1
    f4*       __restrict__ out,    // G x 160 f4
    int G)
{
    const int tid  = threadIdx.x;
    const int g4   = blockIdx.x * GPB;
    const int f    = tid & 15;   // f4 column
    const int r    = tid >> 4;   // row slot 0..15
    const int lane = tid & 63;
    const int w    = tid >> 6;

    // Passthrough copies (zero reuse -> NT both directions), issued first.
    for (int t = tid; t < 96 * GPB; t += 256) {
        const int j = t / 96, k = t % 96;
        const size_t ob = (size_t)(g4 + j) * 160;
        const size_t ib = (size_t)(g4 + j) * 32;
        const int sel = k >> 5, kk = k & 31;
        if (sel == 0)      nts(&out[ob +       kk], ntl(&meta[ib + kk]));
        else if (sel == 1) nts(&out[ob +  96 + kk], ntl(&att [ib + kk]));
        else               nts(&out[ob + 128 + kk], ntl(&cur [ib + kk]));
    }

    int starts[GPB + 1];
    #pragma unroll
    for (int k = 0; k <= GPB; ++k)
        starts[k] = seg[min(g4 + k, G)];

    __shared__ f4 sred[2][4][4][16];  // [buf][stat][wave][f] = 8 KB

    #pragma unroll
    for (int j = 0; j < GPB; ++j) {
        if (g4 + j >= G) break;
        const int start = starts[j];
        const int end   = starts[j + 1];
        const int count = end - start;

        f4 sum = (f4)(0.f);
        f4 sq  = (f4)(0.f);
        f4 mx  = (f4)(-FLT_MAX);
        f4 mn  = (f4)( FLT_MAX);

        int row = start + r;
        for (; row + 48 < end; row += 64) {       // 4 NT loads in flight
            f4 v0 = ntl(&edges[(size_t)(row     ) * 16 + f]);
            f4 v1 = ntl(&edges[(size_t)(row + 16) * 16 + f]);
            f4 v2 = ntl(&edges[(size_t)(row + 32) * 16 + f]);
            f4 v3 = ntl(&edges[(size_t)(row + 48) * 16 + f]);
            ACC(v0); ACC(v1); ACC(v2); ACC(v3);
        }
        for (; row < end; row += 16) {
            f4 v = ntl(&edges[(size_t)row * 16 + f]);
            ACC(v);
        }

        sum = wred_add(sum);
        sq  = wred_add(sq);
        mx  = wred_max(mx);
        mn  = wred_min(mn);

        const int buf = j & 1;
        if (lane < 16) {
            sred[buf][0][w][lane] = sum;
            sred[buf][1][w][lane] = sq;
            sred[buf][2][w][lane] = mx;
            sred[buf][3][w][lane] = mn;
        }
        __syncthreads();   // one barrier per graph (double-buffered LDS)

        if (tid < 64) {
            f4 res;
            if (count == 0) {
                res = (f4)(0.f);
            } else if (r < 2) {          // mean (r==0) or var (r==1)
                f4 S = sred[buf][0][0][f] + sred[buf][0][1][f]
                     + sred[buf][0][2][f] + sred[buf][0][3][f];
                const float inv = 1.0f / (float)count;
                f4 mean = S * inv;
                if (r == 0) {
                    res = mean;
                } else {
                    f4 Q = sred[buf][1][0][f] + sred[buf][1][1][f]
                         + sred[buf][1][2][f] + sred[buf][1][3][f];
                    f4 var = Q * inv - mean * mean;
                    res[0] = fmaxf(var[0], 0.f); res[1] = fmaxf(var[1], 0.f);
                    res[2] = fmaxf(var[2], 0.f); res[3] = fmaxf(var[3], 0.f);
                }
            } else if (r == 2) {         // max
                f4 a = sred[buf][2][0][f], b = sred[buf][2][1][f];
                f4 c = sred[buf][2][2][f], d = sred[buf][2][3][f];
                res[0] = fmaxf(fmaxf(a[0], b[0]), fmaxf(c[0], d[0]));
                res[1] = fmaxf(fmaxf(a[1], b[1]), fmaxf(c[1], d[1]));
                res[2] = fmaxf(fmaxf(a[2], b[2]), fmaxf(c[2], d[2]));
                res[3] = fmaxf(fmaxf(a[3], b[3]), fmaxf(c[3], d[3]));
            } else {                     // min
                f4 a = sred[buf][3][0][f], b = sred[buf][3][1][f];
                f4 c = sred[buf][3][2][f], d = sred[buf][3][3][f];
                res[0] = fminf(fminf(a[0], b[0]), fminf(c[0], d[0]));
                res[1] = fminf(fminf(a[1], b[1]), fminf(c[1], d[1]));
                res[2] = fminf(fminf(a[2], b[2]), fminf(c[2], d[2]));
                res[3] = fminf(fminf(a[3], b[3]), fminf(c[3], d[3]));
            }
            // [32,96) f4 = mean|var|max|min contiguous -> one 1 KB wave NT store
            nts(&out[(size_t)(g4 + j) * 160 + 32 + tid], res);
        }
        // No trailing barrier needed: next graph uses sred[buf^1].
    }
}

extern "C" void kernel_launch(void* const* d_in, const int* in_sizes, int n_in,
                              void* d_out, int out_size, void* d_ws, size_t ws_size,
                              hipStream_t stream)
{
    const float* h_edges = (const float*)d_in[0];
    const float* h_meta  = (const float*)d_in[1];
    const float* h_att   = (const float*)d_in[2];
    const float* h_cur   = (const float*)d_in[3];
    const int*   e_batch = (const int*)d_in[4];

    const int E = in_sizes[4];          // 2,000,000
    const int G = in_sizes[1] / 128;    // 8192

    int* seg = (int*)d_ws;              // (G+1) ints of scratch

    seg_bounds_stream<<<(E + 255) / 256, 256, 0, stream>>>(e_batch, E, G, seg);

    const int nblk = (G + GPB - 1) / GPB;   // 2048 -> exactly 8 blocks/CU
    graph_embed_kernel<<<nblk, 256, 0, stream>>>(
        (const f4*)h_edges, (const f4*)h_meta, (const f4*)h_att,
        (const f4*)h_cur, seg, (f4*)d_out, G);
}